// Round 1
// baseline (209.223 us; speedup 1.0000x reference)
//
#include <hip/hip_runtime.h>
#include <hip/hip_bf16.h>

// Conv2d 3x3 pad=1 stride=1, B=32, 256->256, 56x56, fp32 in/out.
// Implicit GEMM: out[co][px] = sum_k Wr[co][k] * Xcol[px][k], K = 9*256 = 2304,
// k = tap*256 + ci. Channels-last padded input makes Xcol rows K-contiguous.

#define BB   32
#define CINC 256
#define COUTC 256
#define HH   56
#define WW   56
#define HP   58
#define WP   58
#define PIX_PER_IMG (HH*WW)          // 3136
#define NPIX (BB*PIX_PER_IMG)        // 100352
#define KTOT (9*CINC)                // 2304
#define KB_STEPS (KTOT/32)           // 72

#define XT_ELEMS ((size_t)BB*HP*WP*CINC)   // 27,557,888
#define XT_BYTES (XT_ELEMS*2)              // 55,115,776
#define WR_ELEMS ((size_t)COUTC*KTOT)      // 589,824
#define WR_BYTES (WR_ELEMS*2)

#define BM 128
#define BN 128
#define BK 32

using frag_t = __attribute__((ext_vector_type(8))) short;   // 8 bf16
using f32x4  = __attribute__((ext_vector_type(4))) float;

__device__ __forceinline__ void gload_lds16(const void* gsrc, void* ldst) {
  __builtin_amdgcn_global_load_lds(
      (const __attribute__((address_space(1))) unsigned*)gsrc,
      (__attribute__((address_space(3))) unsigned*)ldst, 16, 0, 0);
}

// ---------- pre-pass 1: NCHW fp32 -> padded channels-last bf16 Xt[b][58][58][256]
__global__ void xpose_kernel(const float* __restrict__ inp,
                             __hip_bfloat16* __restrict__ xt) {
  // block handles (b, ci-block of 64, hp): writes xt[b][hp][0..57][cb*64..cb*64+63]
  int bid = blockIdx.x;
  int hp = bid % HP;
  int t  = bid / HP;
  int cb = t % 4;
  int b  = t / 4;
  __shared__ __hip_bfloat16 tile[64 * 60];   // [ci][wp], stride 60 to dodge conflicts
  int tid = threadIdx.x;                     // 256 threads
  for (int i = tid; i < 64 * 60; i += 256) tile[i] = __float2bfloat16(0.f);
  __syncthreads();
  int h = hp - 1;
  if (h >= 0 && h < HH) {
    const float* src = inp + ((size_t)(b * CINC + cb * 64) * HH + h) * WW;
    for (int i = tid; i < 64 * WW; i += 256) {
      int ci = i / WW, w = i - ci * WW;
      tile[ci * 60 + (w + 1)] = __float2bfloat16(src[(size_t)ci * HH * WW + w]);
    }
  }
  __syncthreads();
  __hip_bfloat16* dst = xt + ((size_t)(b * HP + hp) * WP) * CINC + cb * 64;
  for (int i = tid; i < WP * 64; i += 256) {
    int wp = i >> 6, ci = i & 63;
    dst[(size_t)wp * CINC + ci] = tile[ci * 60 + wp];
  }
}

// ---------- pre-pass 2: OIHW fp32 -> Wr[co][k] bf16, k = tap*256 + ci
__global__ void wprep_kernel(const float* __restrict__ k4,
                             __hip_bfloat16* __restrict__ wr) {
  int i = blockIdx.x * 256 + threadIdx.x;
  if (i >= (int)WR_ELEMS) return;
  int co = i / KTOT;
  int k  = i - co * KTOT;
  int tap = k >> 8;
  int ci  = k & 255;
  wr[i] = __float2bfloat16(k4[(co * CINC + ci) * 9 + tap]);
}

// ---------- main implicit-GEMM MFMA kernel (m97 structure, 128x128 tile, BK=32)
__global__ void conv_mfma(const __hip_bfloat16* __restrict__ xt,
                          const __hip_bfloat16* __restrict__ wr,
                          const float* __restrict__ bias,
                          float* __restrict__ out) {
  __shared__ alignas(16) __hip_bfloat16 Alds[BM * BK];  // [co_l][32]
  __shared__ alignas(16) __hip_bfloat16 Blds[BN * BK];  // [px_l][32]

  const int tid  = threadIdx.x;
  const int lane = tid & 63;
  const int wid  = tid >> 6;      // 0..3
  const int wrm  = wid >> 1;      // co half (0/1)
  const int wcn  = wid & 1;       // px half (0/1)
  const int ntile = blockIdx.x;   // 0..783
  const int co0   = blockIdx.y * BM;

  // staging: wave wid issues instructions i = wid*2, wid*2+1 for A and B tiles.
  // granule q = i*64 + lane; row = q>>2, 16B chunk = q&3.
  const int qa0 = wid * 128 + lane;
  const int qa1 = qa0 + 64;
  const char* wr_b = (const char*)wr;
  const char* xt_b = (const char*)xt;

  const size_t a_src0 = ((size_t)(co0 + (qa0 >> 2)) * KTOT + (qa0 & 3) * 8) * 2;
  const size_t a_src1 = ((size_t)(co0 + (qa1 >> 2)) * KTOT + (qa1 & 3) * 8) * 2;

  int pxg0 = ntile * BN + (qa0 >> 2);
  int pxg1 = ntile * BN + (qa1 >> 2);
  int b0 = pxg0 / PIX_PER_IMG, hw0 = pxg0 - b0 * PIX_PER_IMG;
  int b1 = pxg1 / PIX_PER_IMG, hw1 = pxg1 - b1 * PIX_PER_IMG;
  int h0 = hw0 / WW, w0 = hw0 - h0 * WW;
  int h1 = hw1 / WW, w1 = hw1 - h1 * WW;
  const size_t b_src0 = ((((size_t)b0 * HP + h0) * WP + w0) * CINC + (qa0 & 3) * 8) * 2;
  const size_t b_src1 = ((((size_t)b1 * HP + h1) * WP + w1) * CINC + (qa1 & 3) * 8) * 2;

  char* a_dst0 = (char*)Alds + (wid * 2) * 1024;
  char* a_dst1 = (char*)Alds + (wid * 2 + 1) * 1024;
  char* b_dst0 = (char*)Blds + (wid * 2) * 1024;
  char* b_dst1 = (char*)Blds + (wid * 2 + 1) * 1024;

  f32x4 acc[4][4] = {};

  const int g  = lane >> 4;       // k-chunk selector
  const int fr = lane & 15;

  for (int kb = 0; kb < KB_STEPS; ++kb) {
    int tap = kb >> 3;
    int r = tap / 3;
    int s = tap - r * 3;
    int ci0 = (kb & 7) * 32;
    size_t aoff = (size_t)kb * 64;                          // kb*32 elems * 2B
    size_t boff = ((size_t)(r * WP + s) * CINC + ci0) * 2;  // wave-uniform

    __syncthreads();  // previous iteration's frag reads done before overwrite
    gload_lds16(wr_b + a_src0 + aoff, a_dst0);
    gload_lds16(wr_b + a_src1 + aoff, a_dst1);
    gload_lds16(xt_b + b_src0 + boff, b_dst0);
    gload_lds16(xt_b + b_src1 + boff, b_dst1);
    __syncthreads();  // compiler drains vmcnt(0) before barrier -> tiles valid

    frag_t a[4], bf[4];
#pragma unroll
    for (int m = 0; m < 4; ++m) {
      int row = wrm * 64 + m * 16 + fr;
      a[m] = *(const frag_t*)((const char*)Alds + row * 64 + g * 16);
    }
#pragma unroll
    for (int n = 0; n < 4; ++n) {
      int row = wcn * 64 + n * 16 + fr;
      bf[n] = *(const frag_t*)((const char*)Blds + row * 64 + g * 16);
    }
#pragma unroll
    for (int m = 0; m < 4; ++m)
#pragma unroll
      for (int n = 0; n < 4; ++n)
        acc[m][n] = __builtin_amdgcn_mfma_f32_16x16x32_bf16(a[m], bf[n], acc[m][n], 0, 0, 0);
  }

  // epilogue: D lane mapping col = lane&15 (px), row = (lane>>4)*4 + reg (co)
  const int fq = lane >> 4;
  int pb[4], phw[4];
#pragma unroll
  for (int n = 0; n < 4; ++n) {
    int pxg = ntile * BN + wcn * 64 + n * 16 + fr;
    pb[n]  = pxg / PIX_PER_IMG;
    phw[n] = pxg - pb[n] * PIX_PER_IMG;
  }
#pragma unroll
  for (int m = 0; m < 4; ++m) {
#pragma unroll
    for (int rg = 0; rg < 4; ++rg) {
      int co = co0 + wrm * 64 + m * 16 + fq * 4 + rg;
      float bv = bias[co];
#pragma unroll
      for (int n = 0; n < 4; ++n) {
        out[((size_t)pb[n] * COUTC + co) * PIX_PER_IMG + phw[n]] = acc[m][n][rg] + bv;
      }
    }
  }
}

// ---------- correctness fallback if workspace is too small
__global__ void conv_direct(const float* __restrict__ inp,
                            const float* __restrict__ kern,
                            const float* __restrict__ bias,
                            float* __restrict__ out) {
  int idx = blockIdx.x * 256 + threadIdx.x;
  if (idx >= BB * COUTC * PIX_PER_IMG) return;
  int w = idx % WW;
  int t = idx / WW;
  int h = t % HH; t /= HH;
  int co = t % COUTC;
  int b  = t / COUTC;
  float acc = bias[co];
  for (int ci = 0; ci < CINC; ++ci)
    for (int r = 0; r < 3; ++r) {
      int hh = h + r - 1;
      if (hh < 0 || hh >= HH) continue;
      for (int s = 0; s < 3; ++s) {
        int ww2 = w + s - 1;
        if (ww2 < 0 || ww2 >= WW) continue;
        acc += inp[((size_t)(b * CINC + ci) * HH + hh) * WW + ww2] *
               kern[(co * CINC + ci) * 9 + r * 3 + s];
      }
    }
  out[idx] = acc;
}

extern "C" void kernel_launch(void* const* d_in, const int* in_sizes, int n_in,
                              void* d_out, int out_size, void* d_ws, size_t ws_size,
                              hipStream_t stream) {
  const float* inp  = (const float*)d_in[0];
  const float* kern = (const float*)d_in[1];
  const float* bias = (const float*)d_in[2];
  float* out = (float*)d_out;

  size_t need = XT_BYTES + WR_BYTES;
  if (ws_size < need) {
    int tot = BB * COUTC * PIX_PER_IMG;
    conv_direct<<<(tot + 255) / 256, 256, 0, stream>>>(inp, kern, bias, out);
    return;
  }

  __hip_bfloat16* xt  = (__hip_bfloat16*)d_ws;
  __hip_bfloat16* wrp = (__hip_bfloat16*)((char*)d_ws + XT_BYTES);

  xpose_kernel<<<BB * 4 * HP, 256, 0, stream>>>(inp, xt);
  wprep_kernel<<<(int)((WR_ELEMS + 255) / 256), 256, 0, stream>>>(kern, wrp);
  conv_mfma<<<dim3(NPIX / BN, COUTC / BM), 256, 0, stream>>>(xt, wrp, bias, out);
}

// Round 2
// 182.972 us; speedup vs baseline: 1.1435x; 1.1435x over previous
//
#include <hip/hip_runtime.h>
#include <hip/hip_bf16.h>

// Conv2d 3x3 pad=1 stride=1, B=32, 256->256, 56x56, fp32 in/out.
// Implicit GEMM, 256x256 tile, BK=64, 8 waves, 4-phase/K-tile schedule with
// counted vmcnt (T3+T4), LDS XOR-swizzle via pre-swizzled global source (T2),
// setprio around MFMA clusters (T5), XCD-aware block swizzle (T1).

#define BB    32
#define CINC  256
#define COUTC 256
#define HH    56
#define WW    56
#define HP    58
#define WP    58
#define PIX_PER_IMG (HH*WW)          // 3136
#define NPIX  (BB*PIX_PER_IMG)       // 100352
#define KTOT  (9*CINC)               // 2304
#define NKT   36                     // K-tiles of 64

#define XT_ELEMS ((size_t)BB*HP*WP*CINC)
#define XT_BYTES (XT_ELEMS*2)
#define WR_ELEMS ((size_t)COUTC*KTOT)
#define WR_BYTES (WR_ELEMS*2)

#define LDS_BUF  65536
#define LDS_BOFF 32768

using frag_t = __attribute__((ext_vector_type(8))) short;   // 8 bf16
using f32x4  = __attribute__((ext_vector_type(4))) float;

__device__ __forceinline__ void gload_lds16(const void* gsrc, void* ldst) {
  __builtin_amdgcn_global_load_lds(
      (const __attribute__((address_space(1))) unsigned*)gsrc,
      (__attribute__((address_space(3))) unsigned*)ldst, 16, 0, 0);
}

// ---------- pre-pass 1: NCHW fp32 -> padded channels-last bf16 Xt[b][58][58][256]
__global__ void xpose_kernel(const float* __restrict__ inp,
                             __hip_bfloat16* __restrict__ xt) {
  int bid = blockIdx.x;
  int hp = bid % HP;
  int t  = bid / HP;
  int cb = t % 4;
  int b  = t / 4;
  __shared__ __hip_bfloat16 tile[64 * 60];
  int tid = threadIdx.x;
  for (int i = tid; i < 64 * 60; i += 256) tile[i] = __float2bfloat16(0.f);
  __syncthreads();
  int h = hp - 1;
  if (h >= 0 && h < HH) {
    const float* src = inp + ((size_t)(b * CINC + cb * 64) * HH + h) * WW;
    for (int i = tid; i < 64 * WW; i += 256) {
      int ci = i / WW, w = i - ci * WW;
      tile[ci * 60 + (w + 1)] = __float2bfloat16(src[(size_t)ci * HH * WW + w]);
    }
  }
  __syncthreads();
  __hip_bfloat16* dst = xt + ((size_t)(b * HP + hp) * WP) * CINC + cb * 64;
  for (int i = tid; i < WP * 64; i += 256) {
    int wp = i >> 6, ci = i & 63;
    dst[(size_t)wp * CINC + ci] = tile[ci * 60 + wp];
  }
}

// ---------- pre-pass 2: OIHW fp32 -> Wr[co][k] bf16, k = tap*256 + ci
__global__ void wprep_kernel(const float* __restrict__ k4,
                             __hip_bfloat16* __restrict__ wr) {
  int i = blockIdx.x * 256 + threadIdx.x;
  if (i >= (int)WR_ELEMS) return;
  int co = i / KTOT;
  int k  = i - co * KTOT;
  int tap = k >> 8;
  int ci  = k & 255;
  wr[i] = __float2bfloat16(k4[(co * CINC + ci) * 9 + tap]);
}

// ---------- main kernel: 256x256 tile, 8 waves, 4-phase pipelined K-loop
__global__ __launch_bounds__(512, 2) void conv_mfma8(
    const __hip_bfloat16* __restrict__ xt,
    const __hip_bfloat16* __restrict__ wr,
    const float* __restrict__ bias,
    float* __restrict__ out) {
  __shared__ alignas(16) char lds[2 * LDS_BUF];   // 128 KiB: 2 bufs x (A 32K + B 32K)

  const int tid  = threadIdx.x;
  const int lane = tid & 63;
  const int wid  = tid >> 6;      // 0..7
  const int wm   = wid >> 2;      // co half  (0/1): rows wm*128..+127
  const int wn   = wid & 3;       // px quarter:     cols wn*64..+63
  const int fr   = lane & 15;
  const int g    = lane >> 4;

  // XCD swizzle (392 = 8*49, bijective)
  const int bid   = blockIdx.x;
  const int ntile = (bid & 7) * 49 + (bid >> 3);

  const char* wr_b = (const char*)wr;
  const char* xt_b = (const char*)xt;

  // staging: each gload inst fills one 8-row LDS block (1024B, lane-linear).
  // source chunk pre-swizzled: chunk_src = (l&7) ^ ((l>>3)&7) -> LDS(row,c)
  // holds global (row, c ^ (row&7)).
  const int swz   = (((lane & 7) ^ ((lane >> 3) & 7)) << 4);  // bytes
  const int lrow8 = lane >> 3;

  // per-wave inst -> 8-row block assignment, grouped by consumption order:
  //   A-even64 (rows 0-63,128-191)   consumed by phases mh=0
  //   A-odd64  (rows 64-127,192-255) consumed by phases mh=1
  //   B-even32 (row bit5==0)         consumed by phases nh=0
  //   B-odd32  (row bit5==1)         consumed by phases nh=1
  const int j0 = wid * 2, j1 = wid * 2 + 1;
  const int aE0 = ((j0 >> 3) << 4) + (j0 & 7);
  const int aE1 = ((j1 >> 3) << 4) + (j1 & 7);
  const int aO0 = aE0 + 8, aO1 = aE1 + 8;
  const int bE0 = ((j0 >> 2) << 3) + (j0 & 3);
  const int bE1 = ((j1 >> 2) << 3) + (j1 & 3);
  const int bO0 = bE0 + 4, bO1 = bE1 + 4;

  const char* pAe0 = wr_b + (size_t)(aE0 * 8 + lrow8) * (KTOT * 2) + swz;
  const char* pAe1 = wr_b + (size_t)(aE1 * 8 + lrow8) * (KTOT * 2) + swz;
  const char* pAo0 = wr_b + (size_t)(aO0 * 8 + lrow8) * (KTOT * 2) + swz;
  const char* pAo1 = wr_b + (size_t)(aO1 * 8 + lrow8) * (KTOT * 2) + swz;

  auto bsrc = [&](int blk) -> const char* {
    int row = blk * 8 + lrow8;
    int pxg = ntile * 256 + row;
    int b  = pxg / PIX_PER_IMG;
    int hw = pxg - b * PIX_PER_IMG;
    int h = hw / WW, w = hw - h * WW;
    return xt_b + (size_t)((b * HP + h) * WP + w) * (CINC * 2) + swz;
  };
  const char* pBe0 = bsrc(bE0);
  const char* pBe1 = bsrc(bE1);
  const char* pBo0 = bsrc(bO0);
  const char* pBo1 = bsrc(bO1);

  f32x4 acc[8][4] = {};
  frag_t afr[4][2], bfr[2][2];

  auto ldA = [&](int bufr, int mh, int m, int kk) -> frag_t {
    int row = wm * 128 + (mh * 4 + m) * 16 + fr;
    int c = ((kk << 2) | g) ^ (row & 7);
    return *(const frag_t*)(lds + bufr + row * 128 + c * 16);
  };
  auto ldB = [&](int bufr, int nh, int n, int kk) -> frag_t {
    int row = wn * 64 + (nh * 2 + n) * 16 + fr;
    int c = ((kk << 2) | g) ^ (row & 7);
    return *(const frag_t*)(lds + bufr + LDS_BOFF + row * 128 + c * 16);
  };

  // ---- prologue: stage K-tile 0 into buf0, full drain once
  {
    char* d = lds;
    gload_lds16(pAe0, d + aE0 * 1024);
    gload_lds16(pAe1, d + aE1 * 1024);
    gload_lds16(pAo0, d + aO0 * 1024);
    gload_lds16(pAo1, d + aO1 * 1024);
    gload_lds16(pBe0, d + LDS_BOFF + bE0 * 1024);
    gload_lds16(pBe1, d + LDS_BOFF + bE1 * 1024);
    gload_lds16(pBo0, d + LDS_BOFF + bO0 * 1024);
    gload_lds16(pBo1, d + LDS_BOFF + bO1 * 1024);
    asm volatile("s_waitcnt vmcnt(0)" ::: "memory");
    __builtin_amdgcn_s_barrier();
  }

#define MIDBAR()                                              \
  asm volatile("s_waitcnt vmcnt(4)" ::: "memory");            \
  __builtin_amdgcn_s_barrier();                               \
  asm volatile("s_waitcnt lgkmcnt(0)" ::: "memory");          \
  __builtin_amdgcn_sched_barrier(0);                          \
  __builtin_amdgcn_s_setprio(1);

#define ENDBAR()                                              \
  __builtin_amdgcn_s_setprio(0);                              \
  __builtin_amdgcn_s_barrier();

#define MFMAQ(MH, NH)                                                          \
  _Pragma("unroll") for (int kk = 0; kk < 2; ++kk)                             \
  _Pragma("unroll") for (int m = 0; m < 4; ++m)                                \
  _Pragma("unroll") for (int n = 0; n < 2; ++n)                                \
    acc[(MH)*4 + m][(NH)*2 + n] = __builtin_amdgcn_mfma_f32_16x16x32_bf16(     \
        afr[m][kk], bfr[n][kk], acc[(MH)*4 + m][(NH)*2 + n], 0, 0, 0);

  for (int t = 0; t < NKT; ++t) {
    const int t1 = (t + 1 < NKT) ? (t + 1) : (NKT - 1);  // clamped prefetch tile
    const int bufr = (t & 1) * LDS_BUF;
    char* ldsw = lds + ((t + 1) & 1) * LDS_BUF;
    const size_t aoff = (size_t)t1 * 128;                 // t1*64 bf16 * 2B
    const int tap = t1 >> 2;
    const int rr = tap / 3, ss = tap - rr * 3;
    const size_t boff = ((size_t)(rr * WP + ss) * CINC + (size_t)(t1 & 3) * 64) * 2;

    // ---- phase 1: quadrant (mh=0, nh=0); stage A-even(t+1)
#pragma unroll
    for (int kk = 0; kk < 2; ++kk) {
#pragma unroll
      for (int m = 0; m < 4; ++m) afr[m][kk] = ldA(bufr, 0, m, kk);
#pragma unroll
      for (int n = 0; n < 2; ++n) bfr[n][kk] = ldB(bufr, 0, n, kk);
    }
    gload_lds16(pAe0 + aoff, ldsw + aE0 * 1024);
    gload_lds16(pAe1 + aoff, ldsw + aE1 * 1024);
    MIDBAR();
    MFMAQ(0, 0);
    ENDBAR();

    // ---- phase 2: quadrant (mh=0, nh=1); stage B-even(t+1)
#pragma unroll
    for (int kk = 0; kk < 2; ++kk)
#pragma unroll
      for (int n = 0; n < 2; ++n) bfr[n][kk] = ldB(bufr, 1, n, kk);
    gload_lds16(pBe0 + boff, ldsw + LDS_BOFF + bE0 * 1024);
    gload_lds16(pBe1 + boff, ldsw + LDS_BOFF + bE1 * 1024);
    MIDBAR();
    MFMAQ(0, 1);
    ENDBAR();

    // ---- phase 3: quadrant (mh=1, nh=0); stage B-odd(t+1)
#pragma unroll
    for (int kk = 0; kk < 2; ++kk) {
#pragma unroll
      for (int m = 0; m < 4; ++m) afr[m][kk] = ldA(bufr, 1, m, kk);
#pragma unroll
      for (int n = 0; n < 2; ++n) bfr[n][kk] = ldB(bufr, 0, n, kk);
    }
    gload_lds16(pBo0 + boff, ldsw + LDS_BOFF + bO0 * 1024);
    gload_lds16(pBo1 + boff, ldsw + LDS_BOFF + bO1 * 1024);
    MIDBAR();
    MFMAQ(1, 0);
    ENDBAR();

    // ---- phase 4: quadrant (mh=1, nh=1); stage A-odd(t+1)
#pragma unroll
    for (int kk = 0; kk < 2; ++kk)
#pragma unroll
      for (int n = 0; n < 2; ++n) bfr[n][kk] = ldB(bufr, 1, n, kk);
    gload_lds16(pAo0 + aoff, ldsw + aO0 * 1024);
    gload_lds16(pAo1 + aoff, ldsw + aO1 * 1024);
    MIDBAR();
    MFMAQ(1, 1);
    ENDBAR();
  }

  // ---- epilogue: bias + NCHW fp32 store
  int pb[4], phw[4];
#pragma unroll
  for (int nr = 0; nr < 4; ++nr) {
    int pxg = ntile * 256 + wn * 64 + nr * 16 + fr;
    pb[nr]  = pxg / PIX_PER_IMG;
    phw[nr] = pxg - pb[nr] * PIX_PER_IMG;
  }
#pragma unroll
  for (int mr = 0; mr < 8; ++mr) {
#pragma unroll
    for (int rg = 0; rg < 4; ++rg) {
      int co = wm * 128 + mr * 16 + g * 4 + rg;
      float bv = bias[co];
#pragma unroll
      for (int nr = 0; nr < 4; ++nr) {
        out[((size_t)pb[nr] * COUTC + co) * PIX_PER_IMG + phw[nr]] =
            acc[mr][nr][rg] + bv;
      }
    }
  }
}

// ---------- correctness fallback if workspace is too small
__global__ void conv_direct(const float* __restrict__ inp,
                            const float* __restrict__ kern,
                            const float* __restrict__ bias,
                            float* __restrict__ out) {
  int idx = blockIdx.x * 256 + threadIdx.x;
  if (idx >= BB * COUTC * PIX_PER_IMG) return;
  int w = idx % WW;
  int t = idx / WW;
  int h = t % HH; t /= HH;
  int co = t % COUTC;
  int b  = t / COUTC;
  float acc = bias[co];
  for (int ci = 0; ci < CINC; ++ci)
    for (int r = 0; r < 3; ++r) {
      int hh = h + r - 1;
      if (hh < 0 || hh >= HH) continue;
      for (int s = 0; s < 3; ++s) {
        int ww2 = w + s - 1;
        if (ww2 < 0 || ww2 >= WW) continue;
        acc += inp[((size_t)(b * CINC + ci) * HH + hh) * WW + ww2] *
               kern[(co * CINC + ci) * 9 + r * 3 + s];
      }
    }
  out[idx] = acc;
}

extern "C" void kernel_launch(void* const* d_in, const int* in_sizes, int n_in,
                              void* d_out, int out_size, void* d_ws, size_t ws_size,
                              hipStream_t stream) {
  const float* inp  = (const float*)d_in[0];
  const float* kern = (const float*)d_in[1];
  const float* bias = (const float*)d_in[2];
  float* out = (float*)d_out;

  size_t need = XT_BYTES + WR_BYTES;
  if (ws_size < need) {
    int tot = BB * COUTC * PIX_PER_IMG;
    conv_direct<<<(tot + 255) / 256, 256, 0, stream>>>(inp, kern, bias, out);
    return;
  }

  __hip_bfloat16* xt  = (__hip_bfloat16*)d_ws;
  __hip_bfloat16* wrp = (__hip_bfloat16*)((char*)d_ws + XT_BYTES);

  xpose_kernel<<<BB * 4 * HP, 256, 0, stream>>>(inp, xt);
  wprep_kernel<<<(int)((WR_ELEMS + 255) / 256), 256, 0, stream>>>(kern, wrp);
  conv_mfma8<<<NPIX / 256, 512, 0, stream>>>(xt, wrp, bias, out);
}